// Round 1
// baseline (783.963 us; speedup 1.0000x reference)
//
#include <hip/hip_runtime.h>

// ---------------------------------------------------------------------------
// Linformer self-attention, MI355X (gfx950).
// All matmuls as C = A * B^T via one f16-MFMA kernel (m97 structure:
// 128x128 tile, BK=64, global_load_lds width-16 staging, ds_read_b128 frags).
// fp16 chosen over bf16: softmax is near-argmax (score std ~26); bf16 score
// error (~0.05) would blow the 2%-of-absmax threshold on near-tied rows.
// Refactor: K_proj = (Hk^T x) Wk + colsum(Hk) (x) b_k  -> 146 GF total.
// ---------------------------------------------------------------------------

typedef __attribute__((ext_vector_type(8))) _Float16 half8;
typedef __attribute__((ext_vector_type(4))) _Float16 half4;
typedef __attribute__((ext_vector_type(4))) float f32x4;

#define AS1 __attribute__((address_space(1)))
#define AS3 __attribute__((address_space(3)))

__device__ __forceinline__ void gld_lds16(const void* g, void* l) {
    // async global->LDS, 16B per lane; LDS dest = wave-uniform base + lane*16
    __builtin_amdgcn_global_load_lds((AS1 void*)g, (AS3 void*)l, 16, 0, 0);
}

template <typename T> __device__ __forceinline__ T to_out(float v);
template <> __device__ __forceinline__ float    to_out<float>(float v) { return v; }
template <> __device__ __forceinline__ _Float16 to_out<_Float16>(float v) { return (_Float16)v; }

// ---------------------------------------------------------------------------
// C[m,n] = scale * sum_k A[m,k]*B[n,k]  (+ bias[n]), batched via blockIdx.z.
// A: [M,Kd] f16 row-major (lda), B: [N,Kd] f16 row-major (ldb), C: [M,N].
// M,N multiples of 128; Kd multiple of 64. Block = 256 threads (4 waves),
// each wave owns a 64x64 quadrant = 4x4 MFMA tiles of 16x16.
// ---------------------------------------------------------------------------
template <typename OUT_T>
__global__ __launch_bounds__(256) void gemm_bt(
    const _Float16* __restrict__ A, long bsA, int lda,
    const _Float16* __restrict__ B, long bsB, int ldb,
    OUT_T* __restrict__ C, long bsC, int ldc,
    int Kd, const float* __restrict__ bias, float scale)
{
    A += (long)blockIdx.z * bsA;
    B += (long)blockIdx.z * bsB;
    C += (long)blockIdx.z * bsC;
    const int m0 = blockIdx.y * 128, n0 = blockIdx.x * 128;
    const int tid = threadIdx.x, w = tid >> 6, ln = tid & 63;
    const int wm = (w >> 1) * 64, wn = (w & 1) * 64;

    __shared__ __attribute__((aligned(16))) _Float16 As[128 * 64]; // [m][k] 16KB
    __shared__ __attribute__((aligned(16))) _Float16 Bs[128 * 64]; // [n][k] 16KB

    f32x4 acc[4][4] = {};

    const int cb0 = w * 256;                 // wave's chunk base (8-half chunks)
    const _Float16* Ablk = A + (long)m0 * lda;
    const _Float16* Bblk = B + (long)n0 * ldb;

    for (int k0 = 0; k0 < Kd; k0 += 64) {
        // stage 128x64 A-tile and B-tile; per instr: 64 lanes x 16B, 8 lanes/row
        // -> 128 contiguous global bytes per 8 lanes (coalesced), LDS [row][k].
#pragma unroll
        for (int t = 0; t < 4; ++t) {
            const int cb = cb0 + t * 64;
            const int ci = cb + ln;
            const int r = ci >> 3, kc = ci & 7;
            gld_lds16(Ablk + (long)r * lda + k0 + kc * 8, &As[cb * 8]);
            gld_lds16(Bblk + (long)r * ldb + k0 + kc * 8, &Bs[cb * 8]);
        }
        __syncthreads();
#pragma unroll
        for (int kk = 0; kk < 64; kk += 32) {
            half8 af[4], bf[4];
#pragma unroll
            for (int i = 0; i < 4; ++i) {
                af[i] = *(const half8*)&As[(wm + i * 16 + (ln & 15)) * 64 + kk + (ln >> 4) * 8];
                bf[i] = *(const half8*)&Bs[(wn + i * 16 + (ln & 15)) * 64 + kk + (ln >> 4) * 8];
            }
#pragma unroll
            for (int i = 0; i < 4; ++i)
#pragma unroll
                for (int j = 0; j < 4; ++j)
                    acc[i][j] = __builtin_amdgcn_mfma_f32_16x16x32_f16(af[i], bf[j], acc[i][j], 0, 0, 0);
        }
        __syncthreads();
    }

    // C/D layout (m89/m91-verified): col = lane&15, row = (lane>>4)*4 + reg
    const int crow = m0 + wm + ((ln >> 4) << 2);
    const int ccol = n0 + wn + (ln & 15);
#pragma unroll
    for (int i = 0; i < 4; ++i)
#pragma unroll
        for (int r = 0; r < 4; ++r) {
            const long row = crow + i * 16 + r;
#pragma unroll
            for (int j = 0; j < 4; ++j) {
                const int col = ccol + j * 16;
                float v = acc[i][j][r] * scale;
                if (bias) v += bias[col];
                C[row * ldc + col] = to_out<OUT_T>(v);
            }
        }
}

// fp32 -> f16 elementwise (x -> xh)
__global__ void f2h(const float* __restrict__ in, _Float16* __restrict__ out, long n) {
    long i = ((long)blockIdx.x * 256 + threadIdx.x) * 4;
    if (i + 3 < n) {
        float4 v = *(const float4*)(in + i);
        half4 o;
        o[0] = (_Float16)v.x; o[1] = (_Float16)v.y;
        o[2] = (_Float16)v.z; o[3] = (_Float16)v.w;
        *(half4*)(out + i) = o;
    }
}

// transpose + convert: src fp32 [R][C] (ld=C) -> dst f16 [C][R] (ld=R), batched
__global__ void transpose_f2h(const float* __restrict__ src, _Float16* __restrict__ dst,
                              int R, int C, long sbatch, long dbatch) {
    __shared__ float t[32][33];
    const float* s = src + (long)blockIdx.z * sbatch;
    _Float16* d = dst + (long)blockIdx.z * dbatch;
    const int c0 = blockIdx.x * 32, r0 = blockIdx.y * 32;
    const int tx = threadIdx.x & 31, ty = threadIdx.x >> 5; // 32x8
#pragma unroll
    for (int i = 0; i < 32; i += 8)
        t[ty + i][tx] = s[(long)(r0 + ty + i) * C + c0 + tx];
    __syncthreads();
#pragma unroll
    for (int i = 0; i < 32; i += 8)
        d[(long)(c0 + ty + i) * R + r0 + tx] = (_Float16)t[tx][ty + i];
}

// column sums of Hk and Hv (each [4096][256]) -> sk[256], sv[256]
__global__ void colsum2(const float* __restrict__ Hk, const float* __restrict__ Hv,
                        float* __restrict__ sk, float* __restrict__ sv) {
    const float* H = blockIdx.y ? Hv : Hk;
    float* s = blockIdx.y ? sv : sk;
    const int c = threadIdx.x;
    const long r0 = (long)blockIdx.x * 512;
    float acc = 0.f;
    for (int r = 0; r < 512; ++r) acc += H[(r0 + r) * 256 + c];
    atomicAdd(s + c, acc);
}

// Kp[b][kk][d] += sk[kk]*bk[d]   (bias outer term; zero in practice)
__global__ void add_outer_kp(_Float16* __restrict__ Kp, const float* __restrict__ sk,
                             const float* __restrict__ bk) {
    long i = (long)blockIdx.x * 256 + threadIdx.x; // over 8*256*1024
    int d = i & 1023, kk = (i >> 10) & 255;
    Kp[i] = (_Float16)((float)Kp[i] + sk[kk] * bk[d]);
}

// VpT[b][d][kk] += sv[kk]*bv[d]
__global__ void add_outer_vpt(_Float16* __restrict__ VpT, const float* __restrict__ sv,
                              const float* __restrict__ bv) {
    long i = (long)blockIdx.x * 256 + threadIdx.x; // over 8*1024*256
    int kk = i & 255, d = (i >> 8) & 1023;
    VpT[i] = (_Float16)((float)VpT[i] + sv[kk] * bv[d]);
}

// row-wise softmax: scores fp32 [32768][256] -> weights f16; one wave per row
__global__ void softmax_rows(const float* __restrict__ S, _Float16* __restrict__ W) {
    const long row = (long)blockIdx.x * 4 + (threadIdx.x >> 6);
    const int ln = threadIdx.x & 63;
    float4 v = ((const float4*)(S + row * 256))[ln];
    float m = fmaxf(fmaxf(v.x, v.y), fmaxf(v.z, v.w));
#pragma unroll
    for (int o = 32; o > 0; o >>= 1) m = fmaxf(m, __shfl_xor(m, o, 64));
    float e0 = __expf(v.x - m), e1 = __expf(v.y - m);
    float e2 = __expf(v.z - m), e3 = __expf(v.w - m);
    float s = e0 + e1 + e2 + e3;
#pragma unroll
    for (int o = 32; o > 0; o >>= 1) s += __shfl_xor(s, o, 64);
    const float inv = 1.0f / s;
    half4 o4;
    o4[0] = (_Float16)(e0 * inv); o4[1] = (_Float16)(e1 * inv);
    o4[2] = (_Float16)(e2 * inv); o4[3] = (_Float16)(e3 * inv);
    *(half4*)(W + row * 256 + ln * 4) = o4;
}

extern "C" void kernel_launch(void* const* d_in, const int* in_sizes, int n_in,
                              void* d_out, int out_size, void* d_ws, size_t ws_size,
                              hipStream_t stream) {
    const float* x    = (const float*)d_in[0]; // [8,4096,1024]
    const float* Wq   = (const float*)d_in[1]; // [1024,3072]
    const float* bqkv = (const float*)d_in[2]; // [3072]
    const float* Hk   = (const float*)d_in[3]; // [4096,256]
    const float* Hv   = (const float*)d_in[4]; // [4096,256]
    float* out = (float*)d_out;                // [8,4096,1024]

    char* p = (char*)d_ws;
    auto take = [&](size_t n) { char* r = p; p += (n + 255) & ~(size_t)255; return r; };
    _Float16* xh  = (_Float16*)take(33554432ull * 2); // x as f16 [32768,1024]
    _Float16* xt  = (_Float16*)take(33554432ull * 2); // x^T f16 [8][1024][4096]
    _Float16* Wt  = (_Float16*)take(3145728ull * 2);  // W^T f16 [3072][1024]
    _Float16* Hkt = (_Float16*)take(1048576ull * 2);  // Hk^T [256][4096]
    _Float16* Hvt = (_Float16*)take(1048576ull * 2);  // Hv^T [256][4096]
    _Float16* qh  = (_Float16*)take(33554432ull * 2); // q [32768,1024]
    _Float16* Pk  = (_Float16*)take(2097152ull * 2);  // Hk^T x [8][256][1024]
    _Float16* Pv  = (_Float16*)take(2097152ull * 2);
    _Float16* Kp  = (_Float16*)take(2097152ull * 2);  // K_proj [8][256][1024]
    _Float16* VpT = (_Float16*)take(2097152ull * 2);  // V_proj^T [8][1024][256]
    float*    sk  = (float*)take(512 * 4);            // sk[256] ++ sv[256]
    float*    sv  = sk + 256;
    float*    sc  = (float*)take(8388608ull * 4);     // scores fp32 [8][4096][256]
    _Float16* wts = (_Float16*)take(8388608ull * 2);  // softmax weights f16

    const dim3 B256(256);

    // --- input prep ---
    f2h<<<32768, B256, 0, stream>>>(x, xh, 33554432ll);
    transpose_f2h<<<dim3(32, 128, 8), B256, 0, stream>>>(x, xt, 4096, 1024, 4194304, 4194304);
    transpose_f2h<<<dim3(96, 32, 1), B256, 0, stream>>>(Wq, Wt, 1024, 3072, 0, 0);
    transpose_f2h<<<dim3(8, 128, 1), B256, 0, stream>>>(Hk, Hkt, 4096, 256, 0, 0);
    transpose_f2h<<<dim3(8, 128, 1), B256, 0, stream>>>(Hv, Hvt, 4096, 256, 0, 0);
    hipMemsetAsync(sk, 0, 512 * 4, stream);
    colsum2<<<dim3(8, 2, 1), B256, 0, stream>>>(Hk, Hv, sk, sv);

    // --- q = x Wq + bq : [32768,1024] ---
    gemm_bt<_Float16><<<dim3(8, 256, 1), B256, 0, stream>>>(
        xh, 0, 1024, Wt, 0, 1024, qh, 0, 1024, 1024, bqkv, 1.0f);
    // --- Pk = Hk^T x, Pv = Hv^T x : [8][256][1024], K=4096 ---
    gemm_bt<_Float16><<<dim3(8, 2, 8), B256, 0, stream>>>(
        Hkt, 0, 4096, xt, 4194304, 4096, Pk, 262144, 1024, 4096, nullptr, 1.0f);
    gemm_bt<_Float16><<<dim3(8, 2, 8), B256, 0, stream>>>(
        Hvt, 0, 4096, xt, 4194304, 4096, Pv, 262144, 1024, 4096, nullptr, 1.0f);
    // --- K_proj = Pk Wk : [8][256][1024] (Bt = Wk^T = Wt rows [1024,2048)) ---
    gemm_bt<_Float16><<<dim3(8, 2, 8), B256, 0, stream>>>(
        Pk, 262144, 1024, Wt + 1048576, 0, 1024, Kp, 262144, 1024, 1024, nullptr, 1.0f);
    // --- V_proj^T = Wv^T Pv^T : [8][1024][256] (A = Wt rows [2048,3072)) ---
    gemm_bt<_Float16><<<dim3(2, 8, 8), B256, 0, stream>>>(
        Wt + 2097152, 0, 1024, Pv, 262144, 1024, VpT, 262144, 256, 1024, nullptr, 1.0f);
    // --- bias outer terms (exact algebra; numerically no-op since b=0) ---
    add_outer_kp<<<8192, B256, 0, stream>>>(Kp, sk, bqkv + 1024);
    add_outer_vpt<<<8192, B256, 0, stream>>>(VpT, sv, bqkv + 2048);
    // --- scores = q K_proj^T / 32 : fp32 [8][4096][256] ---
    gemm_bt<float><<<dim3(2, 32, 8), B256, 0, stream>>>(
        qh, 4194304, 1024, Kp, 262144, 1024, sc, 1048576, 256, 1024, nullptr, 0.03125f);
    // --- softmax over K=256 ---
    softmax_rows<<<8192, B256, 0, stream>>>(sc, wts);
    // --- out = weights V_proj : fp32 [8][4096][1024], K=256 ---
    gemm_bt<float><<<dim3(8, 32, 8), B256, 0, stream>>>(
        wts, 1048576, 256, VpT, 262144, 256, out, 4194304, 1024, 256, nullptr, 1.0f);
}

// Round 2
// 612.327 us; speedup vs baseline: 1.2803x; 1.2803x over previous
//
#include <hip/hip_runtime.h>

// ---------------------------------------------------------------------------
// Linformer self-attention, MI355X (gfx950).  Round 2.
// One generic C = scale*(A*B^T) + bias + rowv(x)colv f16-MFMA kernel:
//   - 128x128 tile, BK=64, global_load_lds width-16, ds_read_b128 frags
//   - XCD panel swizzle: same-A blocks co-located per XCD (L2 A-reuse)
//   - XOR bank swizzle on the k-chunk slot: kills the 16-way ds_read_b128
//     conflicts (row stride 128B == one bank sweep)
//   - 3-level z-batching (batch / kv-select / K-split)
// fp16 (not bf16): softmax is near-argmax; bf16 score noise fails threshold.
// ---------------------------------------------------------------------------

typedef __attribute__((ext_vector_type(8))) _Float16 half8;
typedef __attribute__((ext_vector_type(4))) _Float16 half4;
typedef __attribute__((ext_vector_type(4))) float f32x4;

#define AS1 __attribute__((address_space(1)))
#define AS3 __attribute__((address_space(3)))

__device__ __forceinline__ void gld_lds16(const void* g, void* l) {
    __builtin_amdgcn_global_load_lds((AS1 void*)g, (AS3 void*)l, 16, 0, 0);
}

template <typename T> __device__ __forceinline__ T to_out(float v);
template <> __device__ __forceinline__ float    to_out<float>(float v) { return v; }
template <> __device__ __forceinline__ _Float16 to_out<_Float16>(float v) { return (_Float16)v; }

// ---------------------------------------------------------------------------
// C[m,n] = scale * sum_k A[m,k]*B[n,k] (+bias[n]) (+rowv[m]*colv[n])
// blockIdx.x spans NM*NN tiles; blockIdx.z decoded as z0 + nz0*(z1 + nz1*z2).
// ---------------------------------------------------------------------------
template <typename OUT_T, bool SWIZ>
__global__ __launch_bounds__(256) void gemm_bt(
    const _Float16* __restrict__ A, long sA0, long sA1, long sA2, int lda,
    const _Float16* __restrict__ B, long sB0, long sB1, long sB2, int ldb,
    OUT_T* __restrict__ C, long sC0, long sC1, long sC2, int ldc,
    int nz0, int nz1, int NM, int NN, int Kd,
    const float* __restrict__ bias, const float* __restrict__ rowv,
    const float* __restrict__ colv, float scale)
{
    {   // z-decode: 3-level batching
        const int z = blockIdx.z;
        const int z0 = z % nz0, t = z / nz0, z1 = t % nz1, z2 = t / nz1;
        A += z0 * sA0 + z1 * sA1 + z2 * sA2;
        B += z0 * sB0 + z1 * sB1 + z2 * sB2;
        C += z0 * sC0 + z1 * sC1 + z2 * sC2;
    }
    // mn-decode: panel swizzle so the 8 XCDs each keep ONE A-tile hot across
    // all NN n-blocks (linear dispatch -> XCD = id%8; here id%8 == local m).
    int mb, nb;
    if (SWIZ) {  // requires NM % 8 == 0
        const int g = blockIdx.x, r = g % (8 * NN);
        mb = (g / (8 * NN)) * 8 + (r & 7);
        nb = r >> 3;
    } else {
        mb = blockIdx.x % NM;
        nb = blockIdx.x / NM;
    }
    const int tid = threadIdx.x, w = tid >> 6, ln = tid & 63;
    const int wm = (w >> 1) * 64, wn = (w & 1) * 64;

    __shared__ __attribute__((aligned(16))) _Float16 As[128 * 64]; // 16KB
    __shared__ __attribute__((aligned(16))) _Float16 Bs[128 * 64]; // 16KB

    f32x4 acc[4][4] = {};

    const int cb0 = w * 256;                // wave's chunk base (16B chunks)
    const _Float16* Ablk = A + (long)mb * 128 * lda;
    const _Float16* Bblk = B + (long)nb * 128 * ldb;

    const int lr = ln & 15;                 // fragment row-within-16
    const int rs = ln & 7;                  // XOR bank-swizzle key
    const int kq = ln >> 4;                 // k-quad 0..3

    for (int k0 = 0; k0 < Kd; k0 += 64) {
        // stage 128x64 tiles; LDS slot ci*16B holds row ci>>3, k-chunk
        // (ci&7)^(row&7)  -> bank-conflict-free fragment reads later.
#pragma unroll
        for (int t = 0; t < 4; ++t) {
            const int ci = cb0 + t * 64 + ln;
            const int r = ci >> 3, kc = (ci & 7) ^ (r & 7);
            gld_lds16(Ablk + (long)r * lda + k0 + kc * 8, &As[(cb0 + t * 64) * 8]);
            gld_lds16(Bblk + (long)r * ldb + k0 + kc * 8, &Bs[(cb0 + t * 64) * 8]);
        }
        __syncthreads();
#pragma unroll
        for (int kh = 0; kh < 2; ++kh) {    // two K=32 halves
            const int c = (((kh * 4) + kq) ^ rs) * 8;
            half8 af[4], bf[4];
#pragma unroll
            for (int i = 0; i < 4; ++i) {
                af[i] = *(const half8*)&As[(wm + i * 16 + lr) * 64 + c];
                bf[i] = *(const half8*)&Bs[(wn + i * 16 + lr) * 64 + c];
            }
#pragma unroll
            for (int i = 0; i < 4; ++i)
#pragma unroll
                for (int j = 0; j < 4; ++j)
                    acc[i][j] = __builtin_amdgcn_mfma_f32_16x16x32_f16(af[i], bf[j], acc[i][j], 0, 0, 0);
        }
        __syncthreads();
    }

    // C/D layout (m89/m91-verified): col = lane&15, row = (lane>>4)*4 + reg
    const int crow = mb * 128 + wm + (kq << 2);
    const int ccol = nb * 128 + wn + lr;
#pragma unroll
    for (int i = 0; i < 4; ++i)
#pragma unroll
        for (int r = 0; r < 4; ++r) {
            const long row = crow + i * 16 + r;
#pragma unroll
            for (int j = 0; j < 4; ++j) {
                const int col = ccol + j * 16;
                float v = acc[i][j][r] * scale;
                if (bias) v += bias[col];
                if (rowv) v += rowv[row] * colv[col];
                C[row * ldc + col] = to_out<OUT_T>(v);
            }
        }
}

// transpose+convert: src fp32 [R][C] -> dst f16 [C][R]; optionally also the
// straight f16 copy (dsth, same layout as src). Batched via blockIdx.z.
__global__ void transpose_f2h(const float* __restrict__ src, _Float16* __restrict__ dst,
                              _Float16* __restrict__ dsth, int R, int C,
                              long sbatch, long dbatch) {
    __shared__ float t[32][33];
    const float* s = src + (long)blockIdx.z * sbatch;
    _Float16* d = dst + (long)blockIdx.z * dbatch;
    _Float16* dh = dsth ? dsth + (long)blockIdx.z * sbatch : nullptr;
    const int c0 = blockIdx.x * 32, r0 = blockIdx.y * 32;
    const int tx = threadIdx.x & 31, ty = threadIdx.x >> 5; // 32x8
#pragma unroll
    for (int i = 0; i < 32; i += 8) {
        float v = s[(long)(r0 + ty + i) * C + c0 + tx];
        t[ty + i][tx] = v;
        if (dh) dh[(long)(r0 + ty + i) * C + c0 + tx] = (_Float16)v;
    }
    __syncthreads();
#pragma unroll
    for (int i = 0; i < 32; i += 8)
        d[(long)(c0 + ty + i) * R + r0 + tx] = (_Float16)t[tx][ty + i];
}

// column sums of Hk and Hv (each [4096][256]) -> sk[256], sv[256]
__global__ void colsum2(const float* __restrict__ Hk, const float* __restrict__ Hv,
                        float* __restrict__ sk, float* __restrict__ sv) {
    const float* H = blockIdx.y ? Hv : Hk;
    float* s = blockIdx.y ? sv : sk;
    const int c = threadIdx.x;
    const long r0 = (long)blockIdx.x * 512;
    float acc = 0.f;
    for (int r = 0; r < 512; ++r) acc += H[(r0 + r) * 256 + c];
    atomicAdd(s + c, acc);
}

// Pkv[j] = f16(P32[j] + P32[j + 4194304])  (K-split reduction, j over 2*8*256*1024)
__global__ void reduce_kv(const float* __restrict__ P, _Float16* __restrict__ Pkv) {
    const long i = ((long)blockIdx.x * 256 + threadIdx.x) * 4;
    float4 a = *(const float4*)(P + i);
    float4 b = *(const float4*)(P + i + 4194304);
    half4 o;
    o[0] = (_Float16)(a.x + b.x); o[1] = (_Float16)(a.y + b.y);
    o[2] = (_Float16)(a.z + b.z); o[3] = (_Float16)(a.w + b.w);
    *(half4*)(Pkv + i) = o;
}

// row-wise softmax: scores fp32 [32768][256] -> weights f16; one wave per row
__global__ void softmax_rows(const float* __restrict__ S, _Float16* __restrict__ W) {
    const long row = (long)blockIdx.x * 4 + (threadIdx.x >> 6);
    const int ln = threadIdx.x & 63;
    float4 v = ((const float4*)(S + row * 256))[ln];
    float m = fmaxf(fmaxf(v.x, v.y), fmaxf(v.z, v.w));
#pragma unroll
    for (int o = 32; o > 0; o >>= 1) m = fmaxf(m, __shfl_xor(m, o, 64));
    float e0 = __expf(v.x - m), e1 = __expf(v.y - m);
    float e2 = __expf(v.z - m), e3 = __expf(v.w - m);
    float s = e0 + e1 + e2 + e3;
#pragma unroll
    for (int o = 32; o > 0; o >>= 1) s += __shfl_xor(s, o, 64);
    const float inv = 1.0f / s;
    half4 o4;
    o4[0] = (_Float16)(e0 * inv); o4[1] = (_Float16)(e1 * inv);
    o4[2] = (_Float16)(e2 * inv); o4[3] = (_Float16)(e3 * inv);
    *(half4*)(W + row * 256 + ln * 4) = o4;
}

extern "C" void kernel_launch(void* const* d_in, const int* in_sizes, int n_in,
                              void* d_out, int out_size, void* d_ws, size_t ws_size,
                              hipStream_t stream) {
    const float* x    = (const float*)d_in[0]; // [8,4096,1024]
    const float* Wq   = (const float*)d_in[1]; // [1024,3072]
    const float* bqkv = (const float*)d_in[2]; // [3072]
    const float* Hk   = (const float*)d_in[3]; // [4096,256]
    const float* Hv   = (const float*)d_in[4]; // [4096,256]
    float* out = (float*)d_out;                // [8,4096,1024]

    char* p = (char*)d_ws;
    auto take = [&](size_t n) { char* r = p; p += (n + 255) & ~(size_t)255; return r; };
    _Float16* xh  = (_Float16*)take(33554432ull * 2); // x f16 [32768,1024]
    _Float16* xt  = (_Float16*)take(33554432ull * 2); // x^T f16 [8][1024][4096]
    _Float16* Wt  = (_Float16*)take(3145728ull * 2);  // W^T f16 [3072][1024]
    _Float16* Hkv = (_Float16*)take(2097152ull * 2);  // Hk^T ++ Hv^T [2][256][4096]
    _Float16* qh  = (_Float16*)take(33554432ull * 2); // q [32768,1024]
    _Float16* Pkv = (_Float16*)take(4194304ull * 2);  // [2(kv)][8][256][1024]
    _Float16* Kp  = (_Float16*)take(2097152ull * 2);  // K_proj [8][256][1024]
    _Float16* VpT = (_Float16*)take(2097152ull * 2);  // V_proj^T [8][1024][256]
    float*    sk  = (float*)take(512 * 4);            // sk[256] ++ sv[256]
    float*    sv  = sk + 256;
    float*    sc  = (float*)take(8388608ull * 4);     // scores fp32; ALSO P32 partials
    float*    P32 = sc;                               // [2(ks)][2(kv)][8][256][1024] (dead before sc written)
    _Float16* wts = (_Float16*)take(8388608ull * 2);  // softmax weights f16

    const dim3 B256(256);

    // --- input prep ---
    transpose_f2h<<<dim3(32, 128, 8), B256, 0, stream>>>(x, xt, xh, 4096, 1024, 4194304, 4194304);
    transpose_f2h<<<dim3(96, 32, 1), B256, 0, stream>>>(Wq, Wt, nullptr, 1024, 3072, 0, 0);
    transpose_f2h<<<dim3(8, 128, 1), B256, 0, stream>>>(Hk, Hkv, nullptr, 4096, 256, 0, 0);
    transpose_f2h<<<dim3(8, 128, 1), B256, 0, stream>>>(Hv, Hkv + 1048576, nullptr, 4096, 256, 0, 0);
    hipMemsetAsync(sk, 0, 512 * 4, stream);
    colsum2<<<dim3(8, 2, 1), B256, 0, stream>>>(Hk, Hv, sk, sv);

    // --- q = x Wq + bq : [32768,1024], K=1024 ---
    gemm_bt<_Float16, true><<<dim3(2048, 1, 1), B256, 0, stream>>>(
        xh, 0, 0, 0, 1024, Wt, 0, 0, 0, 1024, qh, 0, 0, 0, 1024,
        1, 1, 256, 8, 1024, bqkv, nullptr, nullptr, 1.0f);
    // --- P32 = {Hk,Hv}^T x, K-split 2x2048: z = b + 8*kv + 16*ks (512 blocks) ---
    gemm_bt<float, false><<<dim3(16, 1, 32), B256, 0, stream>>>(
        Hkv, 0, 1048576, 2048, 4096, xt, 4194304, 0, 2048, 4096,
        P32, 262144, 2097152, 4194304, 1024,
        8, 2, 2, 8, 2048, nullptr, nullptr, nullptr, 1.0f);
    reduce_kv<<<4096, B256, 0, stream>>>(P32, Pkv);
    // --- K_proj = Pk Wk + sk (x) bk : [8][256][1024], K=1024 ---
    gemm_bt<_Float16, false><<<dim3(16, 1, 8), B256, 0, stream>>>(
        Pkv, 262144, 0, 0, 1024, Wt + 1048576, 0, 0, 0, 1024,
        Kp, 262144, 0, 0, 1024,
        8, 1, 2, 8, 1024, nullptr, sk, bqkv + 1024, 1.0f);
    // --- V_proj^T = Wv^T Pv^T + bv (x) sv : [8][1024][256], K=1024 ---
    gemm_bt<_Float16, true><<<dim3(16, 1, 8), B256, 0, stream>>>(
        Wt + 2097152, 0, 0, 0, 1024, Pkv + 2097152, 262144, 0, 0, 1024,
        VpT, 262144, 0, 0, 256,
        8, 1, 8, 2, 1024, nullptr, bqkv + 2048, sv, 1.0f);
    // --- scores = q K_proj^T / 32 : fp32 [8][4096][256], K=1024 ---
    gemm_bt<float, true><<<dim3(64, 1, 8), B256, 0, stream>>>(
        qh, 4194304, 0, 0, 1024, Kp, 262144, 0, 0, 1024,
        sc, 1048576, 0, 0, 256,
        8, 1, 32, 2, 1024, nullptr, nullptr, nullptr, 0.03125f);
    // --- softmax over K=256 ---
    softmax_rows<<<8192, B256, 0, stream>>>(sc, wts);
    // --- out = weights V_proj : fp32 [8][4096][1024], K=256 ---
    gemm_bt<float, true><<<dim3(256, 1, 8), B256, 0, stream>>>(
        wts, 1048576, 0, 0, 256, VpT, 262144, 0, 0, 256,
        out, 4194304, 0, 0, 1024,
        8, 1, 32, 8, 256, nullptr, nullptr, nullptr, 1.0f);
}

// Round 3
// 542.337 us; speedup vs baseline: 1.4455x; 1.1291x over previous
//
#include <hip/hip_runtime.h>

// ---------------------------------------------------------------------------
// Linformer self-attention, MI355X (gfx950).  Round 3.
// Algebraic refactor v2: q-GEMM (68.7 GF) and Kp-GEMM eliminated:
//   Gt = Wq*Wk^T (batch-indep, 2.1 GF);  Mt[b] = Pk[b]*Gt^T/32 + sk(x)h
//   scores = x*Mt^T + cb[b],  cb = (Pk*g + sk*(bq.bk))/32
// Generic C = scale*(A*B^T) + bias(+batched) + rowv(x)colv f16-MFMA kernel:
//   128x128 tile, BK=64, global_load_lds width-16, ds_read_b128 frags,
//   XCD panel swizzle (R2: FETCH 266->57MB), XOR bank swizzle (R2: conf->0).
// fp16 (not bf16): softmax is near-argmax; bf16 score noise fails threshold.
// ---------------------------------------------------------------------------

typedef __attribute__((ext_vector_type(8))) _Float16 half8;
typedef __attribute__((ext_vector_type(4))) _Float16 half4;
typedef __attribute__((ext_vector_type(4))) float f32x4;

#define AS1 __attribute__((address_space(1)))
#define AS3 __attribute__((address_space(3)))

__device__ __forceinline__ void gld_lds16(const void* g, void* l) {
    __builtin_amdgcn_global_load_lds((AS1 void*)g, (AS3 void*)l, 16, 0, 0);
}

template <typename T> __device__ __forceinline__ T to_out(float v);
template <> __device__ __forceinline__ float    to_out<float>(float v) { return v; }
template <> __device__ __forceinline__ _Float16 to_out<_Float16>(float v) { return (_Float16)v; }

// ---------------------------------------------------------------------------
// C[m,n] = scale * sum_k A[m,k]*B[n,k] (+bias[n], batched by sb0) (+rowv[m]*colv[n])
// blockIdx.x spans NM*NN tiles; blockIdx.z decoded as z0 + nz0*(z1 + nz1*z2).
// ---------------------------------------------------------------------------
template <typename OUT_T, bool SWIZ>
__global__ __launch_bounds__(256) void gemm_bt(
    const _Float16* __restrict__ A, long sA0, long sA1, long sA2, int lda,
    const _Float16* __restrict__ B, long sB0, long sB1, long sB2, int ldb,
    OUT_T* __restrict__ C, long sC0, long sC1, long sC2, int ldc,
    int nz0, int nz1, int NM, int NN, int Kd,
    const float* __restrict__ bias, long sb0,
    const float* __restrict__ rowv, const float* __restrict__ colv, float scale)
{
    {   // z-decode: 3-level batching
        const int z = blockIdx.z;
        const int z0 = z % nz0, t = z / nz0, z1 = t % nz1, z2 = t / nz1;
        A += z0 * sA0 + z1 * sA1 + z2 * sA2;
        B += z0 * sB0 + z1 * sB1 + z2 * sB2;
        C += z0 * sC0 + z1 * sC1 + z2 * sC2;
        if (bias) bias += (long)z0 * sb0;
    }
    // mn-decode: panel swizzle so the 8 XCDs each keep ONE A-tile hot across
    // all NN n-blocks (linear dispatch -> XCD = id%8; here id%8 == local m).
    int mb, nb;
    if (SWIZ) {  // requires NM % 8 == 0
        const int g = blockIdx.x, r = g % (8 * NN);
        mb = (g / (8 * NN)) * 8 + (r & 7);
        nb = r >> 3;
    } else {
        mb = blockIdx.x % NM;
        nb = blockIdx.x / NM;
    }
    const int tid = threadIdx.x, w = tid >> 6, ln = tid & 63;
    const int wm = (w >> 1) * 64, wn = (w & 1) * 64;

    __shared__ __attribute__((aligned(16))) _Float16 As[128 * 64]; // 16KB
    __shared__ __attribute__((aligned(16))) _Float16 Bs[128 * 64]; // 16KB

    f32x4 acc[4][4] = {};

    const int cb0 = w * 256;                // wave's chunk base (16B chunks)
    const _Float16* Ablk = A + (long)mb * 128 * lda;
    const _Float16* Bblk = B + (long)nb * 128 * ldb;

    const int lr = ln & 15;                 // fragment row-within-16
    const int rs = ln & 7;                  // XOR bank-swizzle key
    const int kq = ln >> 4;                 // k-quad 0..3

    for (int k0 = 0; k0 < Kd; k0 += 64) {
        // stage 128x64 tiles; LDS slot ci*16B holds row ci>>3, k-chunk
        // (ci&7)^(row&7)  -> bank-conflict-free fragment reads later.
#pragma unroll
        for (int t = 0; t < 4; ++t) {
            const int ci = cb0 + t * 64 + ln;
            const int r = ci >> 3, kc = (ci & 7) ^ (r & 7);
            gld_lds16(Ablk + (long)r * lda + k0 + kc * 8, &As[(cb0 + t * 64) * 8]);
            gld_lds16(Bblk + (long)r * ldb + k0 + kc * 8, &Bs[(cb0 + t * 64) * 8]);
        }
        __syncthreads();
#pragma unroll
        for (int kh = 0; kh < 2; ++kh) {    // two K=32 halves
            const int c = (((kh * 4) + kq) ^ rs) * 8;
            half8 af[4], bf[4];
#pragma unroll
            for (int i = 0; i < 4; ++i) {
                af[i] = *(const half8*)&As[(wm + i * 16 + lr) * 64 + c];
                bf[i] = *(const half8*)&Bs[(wn + i * 16 + lr) * 64 + c];
            }
#pragma unroll
            for (int i = 0; i < 4; ++i)
#pragma unroll
                for (int j = 0; j < 4; ++j)
                    acc[i][j] = __builtin_amdgcn_mfma_f32_16x16x32_f16(af[i], bf[j], acc[i][j], 0, 0, 0);
        }
        __syncthreads();
    }

    // C/D layout (m89/m91-verified): col = lane&15, row = (lane>>4)*4 + reg
    const int crow = mb * 128 + wm + (kq << 2);
    const int ccol = nb * 128 + wn + lr;
#pragma unroll
    for (int i = 0; i < 4; ++i)
#pragma unroll
        for (int r = 0; r < 4; ++r) {
            const long row = crow + i * 16 + r;
#pragma unroll
            for (int j = 0; j < 4; ++j) {
                const int col = ccol + j * 16;
                float v = acc[i][j][r] * scale;
                if (bias) v += bias[col];
                if (rowv) v += rowv[row] * colv[col];
                C[row * ldc + col] = to_out<OUT_T>(v);
            }
        }
}

// transpose+convert: src fp32 [R][C] -> dst f16 [C][R]; optionally also the
// straight f16 copy (dsth, same layout as src). Batched via blockIdx.z.
__global__ void transpose_f2h(const float* __restrict__ src, _Float16* __restrict__ dst,
                              _Float16* __restrict__ dsth, int R, int C,
                              long sbatch, long dbatch) {
    __shared__ float t[32][33];
    const float* s = src + (long)blockIdx.z * sbatch;
    _Float16* d = dst + (long)blockIdx.z * dbatch;
    _Float16* dh = dsth ? dsth + (long)blockIdx.z * sbatch : nullptr;
    const int c0 = blockIdx.x * 32, r0 = blockIdx.y * 32;
    const int tx = threadIdx.x & 31, ty = threadIdx.x >> 5; // 32x8
#pragma unroll
    for (int i = 0; i < 32; i += 8) {
        float v = s[(long)(r0 + ty + i) * C + c0 + tx];
        t[ty + i][tx] = v;
        if (dh) dh[(long)(r0 + ty + i) * C + c0 + tx] = (_Float16)v;
    }
    __syncthreads();
#pragma unroll
    for (int i = 0; i < 32; i += 8)
        d[(long)(c0 + ty + i) * R + r0 + tx] = (_Float16)t[tx][ty + i];
}

// column sums of Hk and Hv (each [4096][256]) -> sk[256], sv[256]
__global__ void colsum2(const float* __restrict__ Hk, const float* __restrict__ Hv,
                        float* __restrict__ sk, float* __restrict__ sv) {
    const float* H = blockIdx.y ? Hv : Hk;
    float* s = blockIdx.y ? sv : sk;
    const int c = threadIdx.x;
    const long r0 = (long)blockIdx.x * 512;
    float acc = 0.f;
    for (int r = 0; r < 512; ++r) acc += H[(r0 + r) * 256 + c];
    atomicAdd(s + c, acc);
}

// g[c]=bq.Wk[c,:]/32 ; h[e]=bk.Wq[e,:]/32 ; gh[2048]=bq.bk/32  (one wave each)
__global__ void bias_vecs(const float* __restrict__ W, const float* __restrict__ b,
                          float* __restrict__ gh) {
    const int wid = blockIdx.x * 4 + (threadIdx.x >> 6);
    const int ln = threadIdx.x & 63;
    float acc = 0.f;
    if (wid < 1024) {
        for (int j = 0; j < 16; ++j) { int d = ln + 64 * j; acc += b[d] * W[(long)wid * 3072 + 1024 + d]; }
    } else if (wid < 2048) {
        for (int j = 0; j < 16; ++j) { int d = ln + 64 * j; acc += b[1024 + d] * W[(long)(wid - 1024) * 3072 + d]; }
    } else if (wid == 2048) {
        for (int j = 0; j < 16; ++j) { int d = ln + 64 * j; acc += b[d] * b[1024 + d]; }
    } else return;
#pragma unroll
    for (int o = 32; o > 0; o >>= 1) acc += __shfl_xor(acc, o, 64);
    if (!ln) gh[wid] = acc * 0.03125f;
}

// cb[b*256+kk] = sum_c Pk[b][kk][c]*g[c] + sk[kk]*gh[2048]   (one wave each)
__global__ void cb_kernel(const _Float16* __restrict__ Pk, const float* __restrict__ gh,
                          const float* __restrict__ sk, float* __restrict__ cb) {
    const int wid = blockIdx.x * 4 + (threadIdx.x >> 6); // b*256+kk
    const int ln = threadIdx.x & 63;
    const _Float16* row = Pk + (long)wid * 1024;
    float acc = 0.f;
    for (int j = 0; j < 16; ++j) { int c = ln + 64 * j; acc += (float)row[c] * gh[c]; }
#pragma unroll
    for (int o = 32; o > 0; o >>= 1) acc += __shfl_xor(acc, o, 64);
    if (!ln) cb[wid] = acc + sk[wid & 255] * gh[2048];
}

// Pkv[j] = f16(P32[j] + P32[j + 4194304])  (K-split reduction)
__global__ void reduce_kv(const float* __restrict__ P, _Float16* __restrict__ Pkv) {
    const long i = ((long)blockIdx.x * 256 + threadIdx.x) * 4;
    float4 a = *(const float4*)(P + i);
    float4 b = *(const float4*)(P + i + 4194304);
    half4 o;
    o[0] = (_Float16)(a.x + b.x); o[1] = (_Float16)(a.y + b.y);
    o[2] = (_Float16)(a.z + b.z); o[3] = (_Float16)(a.w + b.w);
    *(half4*)(Pkv + i) = o;
}

// row-wise softmax: scores fp32 [32768][256] -> weights f16; one wave per row
__global__ void softmax_rows(const float* __restrict__ S, _Float16* __restrict__ W) {
    const long row = (long)blockIdx.x * 4 + (threadIdx.x >> 6);
    const int ln = threadIdx.x & 63;
    float4 v = ((const float4*)(S + row * 256))[ln];
    float m = fmaxf(fmaxf(v.x, v.y), fmaxf(v.z, v.w));
#pragma unroll
    for (int o = 32; o > 0; o >>= 1) m = fmaxf(m, __shfl_xor(m, o, 64));
    float e0 = __expf(v.x - m), e1 = __expf(v.y - m);
    float e2 = __expf(v.z - m), e3 = __expf(v.w - m);
    float s = e0 + e1 + e2 + e3;
#pragma unroll
    for (int o = 32; o > 0; o >>= 1) s += __shfl_xor(s, o, 64);
    const float inv = 1.0f / s;
    half4 o4;
    o4[0] = (_Float16)(e0 * inv); o4[1] = (_Float16)(e1 * inv);
    o4[2] = (_Float16)(e2 * inv); o4[3] = (_Float16)(e3 * inv);
    *(half4*)(W + row * 256 + ln * 4) = o4;
}

extern "C" void kernel_launch(void* const* d_in, const int* in_sizes, int n_in,
                              void* d_out, int out_size, void* d_ws, size_t ws_size,
                              hipStream_t stream) {
    const float* x    = (const float*)d_in[0]; // [8,4096,1024]
    const float* Wq   = (const float*)d_in[1]; // [1024,3072]
    const float* bqkv = (const float*)d_in[2]; // [3072]
    const float* Hk   = (const float*)d_in[3]; // [4096,256]
    const float* Hv   = (const float*)d_in[4]; // [4096,256]
    float* out = (float*)d_out;                // [8,4096,1024]

    char* p = (char*)d_ws;
    auto take = [&](size_t n) { char* r = p; p += (n + 255) & ~(size_t)255; return r; };
    _Float16* xh  = (_Float16*)take(33554432ull * 2); // x f16 [32768,1024]
    _Float16* xt  = (_Float16*)take(33554432ull * 2); // x^T f16 [8][1024][4096]
    _Float16* Wt  = (_Float16*)take(3145728ull * 2);  // W^T f16 [3072][1024]
    _Float16* Wh  = (_Float16*)take(3145728ull * 2);  // W f16 [1024][3072]
    _Float16* Hkv = (_Float16*)take(2097152ull * 2);  // Hk^T ++ Hv^T [2][256][4096]
    _Float16* Pkv = (_Float16*)take(4194304ull * 2);  // [2(kv)][8][256][1024]
    _Float16* VpT = (_Float16*)take(2097152ull * 2);  // V_proj^T [8][1024][256]
    _Float16* Gt  = (_Float16*)take(1048576ull * 2);  // Wq*Wk^T [1024][1024]
    _Float16* Mt  = (_Float16*)take(2097152ull * 2);  // [8][256][1024]
    float*    gh  = (float*)take(2049 * 4);           // g[1024] ++ h[1024] ++ bq.bk (all /32)
    float*    sk  = (float*)take(512 * 4);            // sk[256] ++ sv[256]
    float*    sv  = sk + 256;
    float*    cbv = (float*)take(2048 * 4);           // score bias per (b,kk)
    float*    sc  = (float*)take(8388608ull * 4);     // scores fp32; ALSO P32 partials
    float*    P32 = sc;                               // [2ks][2kv][8][256][1024] (dead before sc)
    _Float16* wts = (_Float16*)take(8388608ull * 2);  // softmax weights f16

    const dim3 B256(256);

    // --- input prep ---
    transpose_f2h<<<dim3(32, 128, 8), B256, 0, stream>>>(x, xt, xh, 4096, 1024, 4194304, 4194304);
    transpose_f2h<<<dim3(96, 32, 1), B256, 0, stream>>>(Wq, Wt, Wh, 1024, 3072, 0, 0);
    transpose_f2h<<<dim3(8, 128, 1), B256, 0, stream>>>(Hk, Hkv, nullptr, 4096, 256, 0, 0);
    transpose_f2h<<<dim3(8, 128, 1), B256, 0, stream>>>(Hv, Hkv + 1048576, nullptr, 4096, 256, 0, 0);
    hipMemsetAsync(sk, 0, 512 * 4, stream);
    colsum2<<<dim3(8, 2, 1), B256, 0, stream>>>(Hk, Hv, sk, sv);
    bias_vecs<<<513, B256, 0, stream>>>(Wq, bqkv, gh);

    // --- Gt = Wq*Wk^T : [1024][1024], K=1024 (batch-independent) ---
    gemm_bt<_Float16, true><<<dim3(64, 1, 1), B256, 0, stream>>>(
        Wh, 0, 0, 0, 3072, Wh + 1024, 0, 0, 0, 3072, Gt, 0, 0, 0, 1024,
        1, 1, 8, 8, 1024, nullptr, 0, nullptr, nullptr, 1.0f);
    // --- P32 = {Hk,Hv}^T x, K-split 2x2048: z = b + 8*kv + 16*ks (512 blocks) ---
    gemm_bt<float, false><<<dim3(16, 1, 32), B256, 0, stream>>>(
        Hkv, 0, 1048576, 2048, 4096, xt, 4194304, 0, 2048, 4096,
        P32, 262144, 2097152, 4194304, 1024,
        8, 2, 2, 8, 2048, nullptr, 0, nullptr, nullptr, 1.0f);
    reduce_kv<<<4096, B256, 0, stream>>>(P32, Pkv);
    // --- V_proj^T = Wv^T Pv^T + bv (x) sv : [8][1024][256], K=1024 ---
    gemm_bt<_Float16, true><<<dim3(16, 1, 8), B256, 0, stream>>>(
        Wt + 2097152, 0, 0, 0, 1024, Pkv + 2097152, 262144, 0, 0, 1024,
        VpT, 262144, 0, 0, 256,
        8, 1, 8, 2, 1024, nullptr, 0, bqkv + 2048, sv, 1.0f);
    // --- Mt = Pk*Gt^T/32 + sk (x) h : [8][256][1024], K=1024 ---
    gemm_bt<_Float16, false><<<dim3(16, 1, 8), B256, 0, stream>>>(
        Pkv, 262144, 0, 0, 1024, Gt, 0, 0, 0, 1024,
        Mt, 262144, 0, 0, 1024,
        8, 1, 2, 8, 1024, nullptr, 0, sk, gh + 1024, 0.03125f);
    // --- cb[b][kk] = Pk.g + sk*(bq.bk)  (already /32) ---
    cb_kernel<<<512, B256, 0, stream>>>(Pkv, gh, sk, cbv);
    // --- scores = x*Mt^T + cb : fp32 [8][4096][256], K=1024 ---
    gemm_bt<float, true><<<dim3(64, 1, 8), B256, 0, stream>>>(
        xh, 4194304, 0, 0, 1024, Mt, 262144, 0, 0, 1024,
        sc, 1048576, 0, 0, 256,
        8, 1, 32, 2, 1024, cbv, 256, nullptr, nullptr, 1.0f);
    // --- softmax over K=256 ---
    softmax_rows<<<8192, B256, 0, stream>>>(sc, wts);
    // --- out = weights V_proj : fp32 [8][4096][1024], K=256 ---
    gemm_bt<float, true><<<dim3(256, 1, 8), B256, 0, stream>>>(
        wts, 1048576, 0, 0, 256, VpT, 262144, 0, 0, 256,
        out, 4194304, 0, 0, 1024,
        8, 1, 32, 8, 256, nullptr, 0, nullptr, nullptr, 1.0f);
}

// Round 4
// 514.138 us; speedup vs baseline: 1.5248x; 1.0548x over previous
//
#include <hip/hip_runtime.h>

// ---------------------------------------------------------------------------
// Linformer self-attention, MI355X (gfx950).  Round 4.
//   Gt = Wq*Wk^T;  Mt[b] = Pk[b]*Gt^T/32 + sk(x)h;  scores = x*Mt^T + cb[b]
//   R4: fast 64x64 transpose; scores GEMM fused with softmax (128x256 tile);
//       kv merged into M-dim of the Pkv GEMM.
// Generic gemm_bt: 128x128 tile, BK=64, global_load_lds width-16,
// ds_read_b128 frags, XCD panel swizzle, XOR bank swizzle (0 conflicts, R2).
// fp16 (not bf16): softmax is near-argmax; bf16 score noise fails threshold.
// ---------------------------------------------------------------------------

typedef __attribute__((ext_vector_type(8))) _Float16 half8;
typedef __attribute__((ext_vector_type(4))) _Float16 half4;
typedef __attribute__((ext_vector_type(4))) float f32x4;

#define AS1 __attribute__((address_space(1)))
#define AS3 __attribute__((address_space(3)))

__device__ __forceinline__ void gld_lds16(const void* g, void* l) {
    __builtin_amdgcn_global_load_lds((AS1 void*)g, (AS3 void*)l, 16, 0, 0);
}

template <typename T> __device__ __forceinline__ T to_out(float v);
template <> __device__ __forceinline__ float    to_out<float>(float v) { return v; }
template <> __device__ __forceinline__ _Float16 to_out<_Float16>(float v) { return (_Float16)v; }

// ---------------------------------------------------------------------------
// C[m,n] = scale * sum_k A[m,k]*B[n,k] (+bias[n], batched by sb0) (+rowv[m]*colv[n])
// ---------------------------------------------------------------------------
template <typename OUT_T, bool SWIZ>
__global__ __launch_bounds__(256) void gemm_bt(
    const _Float16* __restrict__ A, long sA0, long sA1, long sA2, int lda,
    const _Float16* __restrict__ B, long sB0, long sB1, long sB2, int ldb,
    OUT_T* __restrict__ C, long sC0, long sC1, long sC2, int ldc,
    int nz0, int nz1, int NM, int NN, int Kd,
    const float* __restrict__ bias, long sb0,
    const float* __restrict__ rowv, const float* __restrict__ colv, float scale)
{
    {   // z-decode: 3-level batching
        const int z = blockIdx.z;
        const int z0 = z % nz0, t = z / nz0, z1 = t % nz1, z2 = t / nz1;
        A += z0 * sA0 + z1 * sA1 + z2 * sA2;
        B += z0 * sB0 + z1 * sB1 + z2 * sB2;
        C += z0 * sC0 + z1 * sC1 + z2 * sC2;
        if (bias) bias += (long)z0 * sb0;
    }
    int mb, nb;
    if (SWIZ) {  // requires NM % 8 == 0: XCD keeps one A-panel hot
        const int g = blockIdx.x, r = g % (8 * NN);
        mb = (g / (8 * NN)) * 8 + (r & 7);
        nb = r >> 3;
    } else {
        mb = blockIdx.x % NM;
        nb = blockIdx.x / NM;
    }
    const int tid = threadIdx.x, w = tid >> 6, ln = tid & 63;
    const int wm = (w >> 1) * 64, wn = (w & 1) * 64;

    __shared__ __attribute__((aligned(16))) _Float16 As[128 * 64];
    __shared__ __attribute__((aligned(16))) _Float16 Bs[128 * 64];

    f32x4 acc[4][4] = {};

    const int cb0 = w * 256;
    const _Float16* Ablk = A + (long)mb * 128 * lda;
    const _Float16* Bblk = B + (long)nb * 128 * ldb;

    const int lr = ln & 15, rs = ln & 7, kq = ln >> 4;

    for (int k0 = 0; k0 < Kd; k0 += 64) {
#pragma unroll
        for (int t = 0; t < 4; ++t) {
            const int ci = cb0 + t * 64 + ln;
            const int r = ci >> 3, kc = (ci & 7) ^ (r & 7);
            gld_lds16(Ablk + (long)r * lda + k0 + kc * 8, &As[(cb0 + t * 64) * 8]);
            gld_lds16(Bblk + (long)r * ldb + k0 + kc * 8, &Bs[(cb0 + t * 64) * 8]);
        }
        __syncthreads();
#pragma unroll
        for (int kh = 0; kh < 2; ++kh) {
            const int c = (((kh * 4) + kq) ^ rs) * 8;
            half8 af[4], bf[4];
#pragma unroll
            for (int i = 0; i < 4; ++i) {
                af[i] = *(const half8*)&As[(wm + i * 16 + lr) * 64 + c];
                bf[i] = *(const half8*)&Bs[(wn + i * 16 + lr) * 64 + c];
            }
#pragma unroll
            for (int i = 0; i < 4; ++i)
#pragma unroll
                for (int j = 0; j < 4; ++j)
                    acc[i][j] = __builtin_amdgcn_mfma_f32_16x16x32_f16(af[i], bf[j], acc[i][j], 0, 0, 0);
        }
        __syncthreads();
    }

    // C/D layout: col = lane&15, row = (lane>>4)*4 + reg
    const int crow = mb * 128 + wm + (kq << 2);
    const int ccol = nb * 128 + wn + lr;
#pragma unroll
    for (int i = 0; i < 4; ++i)
#pragma unroll
        for (int r = 0; r < 4; ++r) {
            const long row = crow + i * 16 + r;
#pragma unroll
            for (int j = 0; j < 4; ++j) {
                const int col = ccol + j * 16;
                float v = acc[i][j][r] * scale;
                if (bias) v += bias[col];
                if (rowv) v += rowv[row] * colv[col];
                C[row * ldc + col] = to_out<OUT_T>(v);
            }
        }
}

// ---------------------------------------------------------------------------
// Fused scores+softmax: wts[b][l][kk] = softmax_kk( x[b][l]:Mt[b][kk] + cb[b][kk] )
// Block = 128 rows x 256 cols (full kk range). Wave = 32 rows x 256 cols.
// ---------------------------------------------------------------------------
__global__ __launch_bounds__(256) void score_softmax(
    const _Float16* __restrict__ A, const _Float16* __restrict__ Bm,
    const float* __restrict__ cb, _Float16* __restrict__ Wts)
{
    const int b = blockIdx.z, mb = blockIdx.x;
    const _Float16* Ab = A + (long)b * 4194304 + (long)mb * 131072;
    const _Float16* Bb = Bm + (long)b * 262144;
    const int tid = threadIdx.x, w = tid >> 6, ln = tid & 63;
    const int lr = ln & 15, rs = ln & 7, kq = ln >> 4;

    __shared__ __attribute__((aligned(16))) _Float16 SM[24576]; // As 8192 | Bs 16384
    _Float16* As = SM;
    _Float16* Bs = SM + 8192;

    f32x4 acc[2][16] = {};

    for (int k0 = 0; k0 < 1024; k0 += 64) {
#pragma unroll
        for (int t = 0; t < 4; ++t) {           // A-tile: 128x64
            const int cbase = w * 256 + t * 64;
            const int ci = cbase + ln, r = ci >> 3, kc = (ci & 7) ^ (r & 7);
            gld_lds16(Ab + (long)r * 1024 + k0 + kc * 8, &As[cbase * 8]);
        }
#pragma unroll
        for (int t = 0; t < 8; ++t) {           // B-tile: 256x64
            const int cbase = w * 512 + t * 64;
            const int ci = cbase + ln, r = ci >> 3, kc = (ci & 7) ^ (r & 7);
            gld_lds16(Bb + (long)r * 1024 + k0 + kc * 8, &Bs[cbase * 8]);
        }
        __syncthreads();
#pragma unroll
        for (int kh = 0; kh < 2; ++kh) {
            const int c = (((kh * 4) + kq) ^ rs) * 8;
            const half8 af0 = *(const half8*)&As[(w * 32 + lr) * 64 + c];
            const half8 af1 = *(const half8*)&As[(w * 32 + 16 + lr) * 64 + c];
#pragma unroll
            for (int j = 0; j < 16; ++j) {
                const half8 bf = *(const half8*)&Bs[(j * 16 + lr) * 64 + c];
                acc[0][j] = __builtin_amdgcn_mfma_f32_16x16x32_f16(af0, bf, acc[0][j], 0, 0, 0);
                acc[1][j] = __builtin_amdgcn_mfma_f32_16x16x32_f16(af1, bf, acc[1][j], 0, 0, 0);
            }
        }
        __syncthreads();
    }

    // lane holds rows (w*32 + i*16 + kq*4 + r), cols (j*16 + lr)
    float cbl[16];
    const float* cbb = cb + b * 256;
#pragma unroll
    for (int j = 0; j < 16; ++j) cbl[j] = cbb[j * 16 + lr];

#pragma unroll
    for (int i = 0; i < 2; ++i)
#pragma unroll
        for (int r = 0; r < 4; ++r) {
            float m = -3.0e38f;
#pragma unroll
            for (int j = 0; j < 16; ++j) {
                float v = acc[i][j][r] + cbl[j];
                acc[i][j][r] = v;
                m = fmaxf(m, v);
            }
            m = fmaxf(m, __shfl_xor(m, 1, 64)); m = fmaxf(m, __shfl_xor(m, 2, 64));
            m = fmaxf(m, __shfl_xor(m, 4, 64)); m = fmaxf(m, __shfl_xor(m, 8, 64));
            float s = 0.f;
#pragma unroll
            for (int j = 0; j < 16; ++j) {
                float e = __expf(acc[i][j][r] - m);
                acc[i][j][r] = e;
                s += e;
            }
            s += __shfl_xor(s, 1, 64); s += __shfl_xor(s, 2, 64);
            s += __shfl_xor(s, 4, 64); s += __shfl_xor(s, 8, 64);
            const float inv = 1.0f / s;
#pragma unroll
            for (int j = 0; j < 16; ++j) acc[i][j][r] *= inv;
        }

    // pack 64-row halves through LDS (pitch 264: 16B-aligned rows, kq->bank spread)
#pragma unroll
    for (int i = 0; i < 2; ++i) {
        __syncthreads();
#pragma unroll
        for (int r = 0; r < 4; ++r)
#pragma unroll
            for (int j = 0; j < 16; ++j)
                SM[(w * 16 + kq * 4 + r) * 264 + j * 16 + lr] = (_Float16)acc[i][j][r];
        __syncthreads();
#pragma unroll
        for (int u = 0; u < 8; ++u) {
            const int idx = tid + 256 * u, row = idx >> 5, ci2 = idx & 31;
            const half8 v = *(const half8*)&SM[row * 264 + ci2 * 8];
            const long grow = (long)b * 4096 + mb * 128 + (row >> 4) * 32 + i * 16 + (row & 15);
            *(half8*)&Wts[grow * 256 + ci2 * 8] = v;
        }
    }
}

// 64x64-tile transpose+convert: src fp32 [R][C] -> dst f16 [C][R];
// optionally straight f16 copy dsth (layout of src). Batched via blockIdx.z.
__global__ __launch_bounds__(256) void tr64(const float* __restrict__ src,
                                            _Float16* __restrict__ dst,
                                            _Float16* __restrict__ dsth,
                                            int R, int C, long sbatch, long dbatch) {
    __shared__ float T[64][68];
    const float* s = src + (long)blockIdx.z * sbatch;
    _Float16* d = dst + (long)blockIdx.z * dbatch;
    _Float16* dh = dsth ? dsth + (long)blockIdx.z * sbatch : nullptr;
    const int c0 = blockIdx.x * 64, r0 = blockIdx.y * 64;
    const int q = threadIdx.x & 15, ry = threadIdx.x >> 4;
#pragma unroll
    for (int rr = 0; rr < 4; ++rr) {
        const int row = ry + rr * 16;
        const float4 v = *(const float4*)(s + (long)(r0 + row) * C + c0 + q * 4);
        *(float4*)&T[row][q * 4] = v;
        if (dh) {
            half4 o;
            o[0] = (_Float16)v.x; o[1] = (_Float16)v.y;
            o[2] = (_Float16)v.z; o[3] = (_Float16)v.w;
            *(half4*)(dh + (long)(r0 + row) * C + c0 + q * 4) = o;
        }
    }
    __syncthreads();
#pragma unroll
    for (int rr = 0; rr < 4; ++rr) {
        const int c = ry + rr * 16;
        half4 o;
#pragma unroll
        for (int u = 0; u < 4; ++u) o[u] = (_Float16)T[q * 4 + u][c];
        *(half4*)(d + (long)(c0 + c) * R + r0 + q * 4) = o;
    }
}

// column sums of Hk and Hv (each [4096][256]) -> sk[256], sv[256]
__global__ void colsum2(const float* __restrict__ Hk, const float* __restrict__ Hv,
                        float* __restrict__ sk, float* __restrict__ sv) {
    const float* H = blockIdx.y ? Hv : Hk;
    float* s = blockIdx.y ? sv : sk;
    const int c = threadIdx.x;
    const long r0 = (long)blockIdx.x * 512;
    float acc = 0.f;
    for (int r = 0; r < 512; ++r) acc += H[(r0 + r) * 256 + c];
    atomicAdd(s + c, acc);
}

// g[c]=bq.Wk[c,:]/32 ; h[e]=bk.Wq[e,:]/32 ; gh[2048]=bq.bk/32  (one wave each)
__global__ void bias_vecs(const float* __restrict__ W, const float* __restrict__ b,
                          float* __restrict__ gh) {
    const int wid = blockIdx.x * 4 + (threadIdx.x >> 6);
    const int ln = threadIdx.x & 63;
    float acc = 0.f;
    if (wid < 1024) {
        for (int j = 0; j < 16; ++j) { int d = ln + 64 * j; acc += b[d] * W[(long)wid * 3072 + 1024 + d]; }
    } else if (wid < 2048) {
        for (int j = 0; j < 16; ++j) { int d = ln + 64 * j; acc += b[1024 + d] * W[(long)(wid - 1024) * 3072 + d]; }
    } else if (wid == 2048) {
        for (int j = 0; j < 16; ++j) { int d = ln + 64 * j; acc += b[d] * b[1024 + d]; }
    } else return;
#pragma unroll
    for (int o = 32; o > 0; o >>= 1) acc += __shfl_xor(acc, o, 64);
    if (!ln) gh[wid] = acc * 0.03125f;
}

// cb[b*256+kk] = sum_c Pk[b][kk][c]*g[c] + sk[kk]*gh[2048]   (one wave each)
__global__ void cb_kernel(const _Float16* __restrict__ Pk, const float* __restrict__ gh,
                          const float* __restrict__ sk, float* __restrict__ cb) {
    const int wid = blockIdx.x * 4 + (threadIdx.x >> 6);
    const int ln = threadIdx.x & 63;
    const _Float16* row = Pk + (long)wid * 1024;
    float acc = 0.f;
    for (int j = 0; j < 16; ++j) { int c = ln + 64 * j; acc += (float)row[c] * gh[c]; }
#pragma unroll
    for (int o = 32; o > 0; o >>= 1) acc += __shfl_xor(acc, o, 64);
    if (!ln) cb[wid] = acc + sk[wid & 255] * gh[2048];
}

// Pkv[kv][b][kk][d] = f16( P32[0][b][kv*256+kk][d] + P32[1][b][kv*256+kk][d] )
__global__ void reduce_kv(const float* __restrict__ P, _Float16* __restrict__ Pkv) {
    const long o = ((long)blockIdx.x * 256 + threadIdx.x) * 4;
    const int kv = (int)(o >> 21), b = (int)(o >> 18) & 7;
    const long r = o & 262143;
    const long i = (long)b * 524288 + (long)kv * 262144 + r;
    float4 a = *(const float4*)(P + i);
    float4 bb = *(const float4*)(P + i + 4194304);
    half4 out;
    out[0] = (_Float16)(a.x + bb.x); out[1] = (_Float16)(a.y + bb.y);
    out[2] = (_Float16)(a.z + bb.z); out[3] = (_Float16)(a.w + bb.w);
    *(half4*)(Pkv + o) = out;
}

extern "C" void kernel_launch(void* const* d_in, const int* in_sizes, int n_in,
                              void* d_out, int out_size, void* d_ws, size_t ws_size,
                              hipStream_t stream) {
    const float* x    = (const float*)d_in[0]; // [8,4096,1024]
    const float* Wq   = (const float*)d_in[1]; // [1024,3072]
    const float* bqkv = (const float*)d_in[2]; // [3072]
    const float* Hk   = (const float*)d_in[3]; // [4096,256]
    const float* Hv   = (const float*)d_in[4]; // [4096,256]
    float* out = (float*)d_out;                // [8,4096,1024]

    char* p = (char*)d_ws;
    auto take = [&](size_t n) { char* r = p; p += (n + 255) & ~(size_t)255; return r; };
    _Float16* xh  = (_Float16*)take(33554432ull * 2); // x f16 [32768,1024]
    _Float16* xt  = (_Float16*)take(33554432ull * 2); // x^T f16 [8][1024][4096]
    _Float16* Wt  = (_Float16*)take(3145728ull * 2);  // W^T f16 [3072][1024]
    _Float16* Wh  = (_Float16*)take(3145728ull * 2);  // W f16 [1024][3072]
    _Float16* Hkv = (_Float16*)take(2097152ull * 2);  // Hk^T ++ Hv^T = [512][4096]
    _Float16* Pkv = (_Float16*)take(4194304ull * 2);  // [2(kv)][8][256][1024]
    _Float16* VpT = (_Float16*)take(2097152ull * 2);  // V_proj^T [8][1024][256]
    _Float16* Gt  = (_Float16*)take(1048576ull * 2);  // [1024 d][1024 c]
    _Float16* Mt  = (_Float16*)take(2097152ull * 2);  // [8][256][1024]
    float*    gh  = (float*)take(2049 * 4);           // g[1024] ++ h[1024] ++ bq.bk/32
    float*    sk  = (float*)take(512 * 4);            // sk[256] ++ sv[256]
    float*    sv  = sk + 256;
    float*    cbv = (float*)take(2048 * 4);           // score bias per (b,kk)
    float*    P32 = (float*)take(8388608ull * 4);     // [2ks][8b][512][1024]
    _Float16* wts = (_Float16*)take(8388608ull * 2);  // softmax weights f16

    const dim3 B256(256);

    // --- input prep ---
    tr64<<<dim3(16, 64, 8), B256, 0, stream>>>(x, xt, xh, 4096, 1024, 4194304, 4194304);
    tr64<<<dim3(48, 16, 1), B256, 0, stream>>>(Wq, Wt, Wh, 1024, 3072, 0, 0);
    tr64<<<dim3(4, 64, 1), B256, 0, stream>>>(Hk, Hkv, nullptr, 4096, 256, 0, 0);
    tr64<<<dim3(4, 64, 1), B256, 0, stream>>>(Hv, Hkv + 1048576, nullptr, 4096, 256, 0, 0);
    hipMemsetAsync(sk, 0, 512 * 4, stream);
    colsum2<<<dim3(8, 2, 1), B256, 0, stream>>>(Hk, Hv, sk, sv);
    bias_vecs<<<513, B256, 0, stream>>>(Wq, bqkv, gh);

    // --- Gt[d][c] = sum_e W[d][e]*W[c][1024+e] : K=1024 ---
    gemm_bt<_Float16, true><<<dim3(64, 1, 1), B256, 0, stream>>>(
        Wh, 0, 0, 0, 3072, Wh + 1024, 0, 0, 0, 3072, Gt, 0, 0, 0, 1024,
        1, 1, 8, 8, 1024, nullptr, 0, nullptr, nullptr, 1.0f);
    // --- P32 = Hkv^T-stacked x, kv merged into M (512 rows), K-split 2x2048:
    //     z = b + 8*ks (16 z-blocks x 32 mn-blocks) ---
    gemm_bt<float, false><<<dim3(32, 1, 16), B256, 0, stream>>>(
        Hkv, 0, 2048, 0, 4096, xt, 4194304, 2048, 0, 4096,
        P32, 524288, 4194304, 0, 1024,
        8, 2, 4, 8, 2048, nullptr, 0, nullptr, nullptr, 1.0f);
    reduce_kv<<<4096, B256, 0, stream>>>(P32, Pkv);
    // --- V_proj^T = Wv^T Pv^T + bv (x) sv : [8][1024][256], K=1024 ---
    gemm_bt<_Float16, true><<<dim3(16, 1, 8), B256, 0, stream>>>(
        Wt + 2097152, 0, 0, 0, 1024, Pkv + 2097152, 262144, 0, 0, 1024,
        VpT, 262144, 0, 0, 256,
        8, 1, 8, 2, 1024, nullptr, 0, bqkv + 2048, sv, 1.0f);
    // --- Mt = Pk*Gt^T/32 + sk (x) h : [8][256][1024], K=1024 ---
    gemm_bt<_Float16, false><<<dim3(16, 1, 8), B256, 0, stream>>>(
        Pkv, 262144, 0, 0, 1024, Gt, 0, 0, 0, 1024,
        Mt, 262144, 0, 0, 1024,
        8, 1, 2, 8, 1024, nullptr, 0, sk, gh + 1024, 0.03125f);
    // --- cb[b][kk] = Pk.g + sk*(bq.bk)  (already /32) ---
    cb_kernel<<<512, B256, 0, stream>>>(Pkv, gh, sk, cbv);
    // --- fused scores+softmax -> wts f16 [8][4096][256] ---
    score_softmax<<<dim3(32, 1, 8), B256, 0, stream>>>(xh, Mt, cbv, wts);
    // --- out = weights V_proj : fp32 [8][4096][1024], K=256 ---
    gemm_bt<float, true><<<dim3(256, 1, 8), B256, 0, stream>>>(
        wts, 1048576, 0, 0, 256, VpT, 262144, 0, 0, 256,
        out, 4194304, 0, 0, 1024,
        8, 1, 32, 8, 256, nullptr, 0, nullptr, nullptr, 1.0f);
}